// Round 2
// baseline (300.235 us; speedup 1.0000x reference)
//
#include <hip/hip_runtime.h>
#include <hip/hip_bf16.h>

// Problem dims
#define NPIX 4096   // 64*64
#define FEPS 1e-5f

// ws float-region layout (element offsets into (float*)d_ws)
// word 0 (as int): dtype flag written by k_probe (1 = bf16, 2 = fp32)
#define OFF_FOLD 64     // 448 floats: A1[16] B1[16] A2[64] B2[64] gA1[16] gB1[16] gA2[64] gB2[64] cA[64] cB[64]
#define OFF_G    512    // 512 floats: per (b,c) channel means
#define OFF_LW1  1024   // 1024
#define OFF_LW2  2048   // 1024
#define OFF_GW1  3072   // 1024
#define OFF_GW2  4096   // 1024
#define OFF_WT   5120   // 36864 floats: conv w transposed, [(ic*9 + tap)*64 + oc]
#define OFF_XO_BYTES ((5120 + 36864) * 4)   // bf16 xo[8][64][4096] after float region

typedef __hip_bfloat16 bf16;

template<typename T> __device__ __forceinline__ float ldf(const T* p);
template<> __device__ __forceinline__ float ldf<bf16>(const bf16* p)  { return __bfloat162float(*p); }
template<> __device__ __forceinline__ float ldf<float>(const float* p){ return *p; }

template<typename T> __device__ __forceinline__ void stf(T* p, float v);
template<> __device__ __forceinline__ void stf<bf16>(bf16* p, float v)  { *p = __float2bfloat16(v); }
template<> __device__ __forceinline__ void stf<float>(float* p, float v){ *p = v; }

// ---------------------------------------------------------------------------
// dtype probe: low 16 bits of each 32-bit word of N(0,1) bf16 data are a bf16
// value (exponent concentrated near 127); for fp32 data they are uniform
// mantissa bits. Count hits in a wide exponent window over 64 words.
// ---------------------------------------------------------------------------
__global__ void k_probe(const unsigned* __restrict__ x, int* __restrict__ flag)
{
    int t = threadIdx.x;
    unsigned w = x[t];
    unsigned h = w & 0xffffu;
    int e = (int)((h >> 7) & 0xff);
    int hit = (h == 0u || (e >= 96 && e <= 160)) ? 1 : 0;
    unsigned long long m = __ballot(hit);
    if (t == 0) flag[0] = (__popcll(m) >= 40) ? 1 : 2;   // bf16 ~64 hits, fp32 ~16
}

// ---------------------------------------------------------------------------
struct PrepArgs { const void* p[30]; };
// slots: 0..5 lw1 lb1 ls1 lbb1 lm1 lv1 | 6..11 lw2 lb2 ls2 lbb2 lm2 lv2
//        12..17 gw1 gb1 gs1 gbb1 gm1 gv1 | 18..23 gw2 gb2 gs2 gbb2 gm2 gv2
//        24..29 cw cb cs cbb cm cv

template<typename T, int ID>
__global__ void k_prep_t(PrepArgs a, float* __restrict__ ws)
{
    if (((const int*)ws)[0] != ID) return;
    const T* lw1  = (const T*)a.p[0];  const T* lb1  = (const T*)a.p[1];
    const T* ls1  = (const T*)a.p[2];  const T* lbb1 = (const T*)a.p[3];
    const T* lm1  = (const T*)a.p[4];  const T* lv1  = (const T*)a.p[5];
    const T* lw2  = (const T*)a.p[6];  const T* lb2  = (const T*)a.p[7];
    const T* ls2  = (const T*)a.p[8];  const T* lbb2 = (const T*)a.p[9];
    const T* lm2  = (const T*)a.p[10]; const T* lv2  = (const T*)a.p[11];
    const T* gw1  = (const T*)a.p[12]; const T* gb1  = (const T*)a.p[13];
    const T* gs1  = (const T*)a.p[14]; const T* gbb1 = (const T*)a.p[15];
    const T* gm1  = (const T*)a.p[16]; const T* gv1  = (const T*)a.p[17];
    const T* gw2  = (const T*)a.p[18]; const T* gb2  = (const T*)a.p[19];
    const T* gs2  = (const T*)a.p[20]; const T* gbb2 = (const T*)a.p[21];
    const T* gm2  = (const T*)a.p[22]; const T* gv2  = (const T*)a.p[23];
    const T* cw   = (const T*)a.p[24]; const T* cb   = (const T*)a.p[25];
    const T* cs   = (const T*)a.p[26]; const T* cbb  = (const T*)a.p[27];
    const T* cm   = (const T*)a.p[28]; const T* cv   = (const T*)a.p[29];

    int bx = blockIdx.x;
    int tid = threadIdx.x;
    if (bx < 16) {
        // transpose conv weights: wT[(ic*9+k)*64 + oc] = cw[oc*576 + ic*9 + k]
        int ic0 = bx * 4;
        for (int e = tid; e < 2304; e += 256) {
            int icl = e / 576;
            int rem = e % 576;
            int k   = rem / 64;
            int oc  = rem % 64;
            int ic  = ic0 + icl;
            ws[OFF_WT + (ic * 9 + k) * 64 + oc] = ldf(cw + oc * 576 + ic * 9 + k);
        }
    } else if (bx == 16) {
        for (int e = tid; e < 4096; e += 256) {
            if (e < 1024)      ws[OFF_LW1 + e]        = ldf(lw1 + e);
            else if (e < 2048) ws[OFF_LW2 + e - 1024] = ldf(lw2 + e - 1024);
            else if (e < 3072) ws[OFF_GW1 + e - 2048] = ldf(gw1 + e - 2048);
            else               ws[OFF_GW2 + e - 3072] = ldf(gw2 + e - 3072);
        }
    } else {
        if (tid < 16) {
            float inv = ldf(ls1 + tid) * rsqrtf(ldf(lv1 + tid) + FEPS);
            ws[OFF_FOLD + 0  + tid] = inv;
            ws[OFF_FOLD + 16 + tid] = ldf(lb1 + tid) * inv + ldf(lbb1 + tid) - ldf(lm1 + tid) * inv;
            float ginv = ldf(gs1 + tid) * rsqrtf(ldf(gv1 + tid) + FEPS);
            ws[OFF_FOLD + 160 + tid] = ginv;
            ws[OFF_FOLD + 176 + tid] = ldf(gb1 + tid) * ginv + ldf(gbb1 + tid) - ldf(gm1 + tid) * ginv;
        }
        if (tid < 64) {
            float inv2 = ldf(ls2 + tid) * rsqrtf(ldf(lv2 + tid) + FEPS);
            ws[OFF_FOLD + 32 + tid] = inv2;
            ws[OFF_FOLD + 96 + tid] = ldf(lb2 + tid) * inv2 + ldf(lbb2 + tid) - ldf(lm2 + tid) * inv2;
            float ginv2 = ldf(gs2 + tid) * rsqrtf(ldf(gv2 + tid) + FEPS);
            ws[OFF_FOLD + 192 + tid] = ginv2;
            ws[OFF_FOLD + 256 + tid] = ldf(gb2 + tid) * ginv2 + ldf(gbb2 + tid) - ldf(gm2 + tid) * ginv2;
            float cinv = ldf(cs + tid) * rsqrtf(ldf(cv + tid) + FEPS);
            ws[OFF_FOLD + 320 + tid] = cinv;
            ws[OFF_FOLD + 384 + tid] = ldf(cb + tid) * cinv + ldf(cbb + tid) - ldf(cm + tid) * cinv;
        }
    }
}

// ---------------------------------------------------------------------------
// channel means: grid 512 (one per (b,c)), block 256, 16 elements/thread.
// ---------------------------------------------------------------------------
template<typename T, int ID>
__global__ void k_means_t(const void* __restrict__ xv, float* __restrict__ ws)
{
    if (((const int*)ws)[0] != ID) return;
    const T* x = (const T*)xv + (size_t)blockIdx.x * NPIX;
    int t = threadIdx.x;
    float s = 0.f;
#pragma unroll
    for (int i = 0; i < 16; ++i) s += ldf(x + t * 16 + i);
#pragma unroll
    for (int off = 32; off > 0; off >>= 1) s += __shfl_down(s, off, 64);
    __shared__ float red[4];
    if ((t & 63) == 0) red[t >> 6] = s;
    __syncthreads();
    if (t == 0)
        ws[OFF_G + blockIdx.x] = (red[0] + red[1] + red[2] + red[3]) * (1.0f / 4096.0f);
}

// ---------------------------------------------------------------------------
// local MLP + global MLP + sigmoid gate -> xo (bf16, in ws)
// grid 256, block 128: 128 consecutive pixels of one image per block.
// ---------------------------------------------------------------------------
template<typename T, int ID>
__global__ void k_gate_t(const void* __restrict__ xv, float* __restrict__ ws,
                         bf16* __restrict__ xo)
{
    if (((const int*)ws)[0] != ID) return;
    int b = blockIdx.x >> 5;
    int n = (blockIdx.x & 31) * 128 + threadIdx.x;
    int tid = threadIdx.x;

    __shared__ float t1[16];
    __shared__ float xg[64];
    if (tid < 16) {
        float s = 0.f;
#pragma unroll
        for (int c = 0; c < 64; ++c)
            s += ws[OFF_GW1 + tid * 64 + c] * ws[OFF_G + b * 64 + c];
        float z = ws[OFF_FOLD + 160 + tid] * s + ws[OFF_FOLD + 176 + tid];
        t1[tid] = fmaxf(z, 0.f);
    }
    __syncthreads();
    if (tid < 64) {
        float s = 0.f;
#pragma unroll
        for (int j = 0; j < 16; ++j)
            s += ws[OFF_GW2 + tid * 16 + j] * t1[j];
        xg[tid] = ws[OFF_FOLD + 192 + tid] * s + ws[OFF_FOLD + 256 + tid];
    }
    __syncthreads();

    const T* xb = (const T*)xv + (size_t)b * 64 * NPIX + n;
    float xr[64];
#pragma unroll
    for (int c = 0; c < 64; ++c) xr[c] = ldf(xb + c * NPIX);

    float h[16];
#pragma unroll
    for (int i = 0; i < 16; ++i) {
        float s = 0.f;
#pragma unroll
        for (int c = 0; c < 64; ++c) s += ws[OFF_LW1 + i * 64 + c] * xr[c];
        float z = ws[OFF_FOLD + 0 + i] * s + ws[OFF_FOLD + 16 + i];
        h[i] = fmaxf(z, 0.f);
    }

    bf16* xob = xo + (size_t)b * 64 * NPIX + n;
#pragma unroll
    for (int c = 0; c < 64; ++c) {
        float s = 0.f;
#pragma unroll
        for (int j = 0; j < 16; ++j) s += ws[OFF_LW2 + c * 16 + j] * h[j];
        float z = ws[OFF_FOLD + 32 + c] * s + ws[OFF_FOLD + 96 + c] + xg[c];
        float sg = 1.0f / (1.0f + __expf(-z));
        xob[c * NPIX] = __float2bfloat16(xr[c] * sg);
    }
}

// ---------------------------------------------------------------------------
// 3x3 SAME conv + folded BN + relu.
// grid (16 strips, 8 batch, 4 oc-quarters), block 256 (one thread per pixel
// of a 4-row strip). 16 fp32 accumulators/thread; weights from transposed wT.
// ---------------------------------------------------------------------------
template<typename T, int ID>
__global__ void k_conv_t(const bf16* __restrict__ xo, const float* __restrict__ ws,
                         void* __restrict__ outv)
{
    if (((const int*)ws)[0] != ID) return;
    int strip = blockIdx.x;
    int b     = blockIdx.y;
    int ocq   = blockIdx.z;
    int ocBase = ocq * 16;
    int tid = threadIdx.x;
    int row = strip * 4 + (tid >> 6);
    int col = tid & 63;

    bool rv0 = (row >= 1);
    bool rv2 = (row <= 62);
    bool cv0 = (col >= 1);
    bool cv2 = (col <= 62);

    float acc[16];
#pragma unroll
    for (int i = 0; i < 16; ++i) acc[i] = 0.f;

    const bf16* xb = xo + (size_t)b * 64 * NPIX + row * 64 + col;
    const float* wt = ws + OFF_WT + ocBase;

#pragma unroll 2
    for (int ic = 0; ic < 64; ++ic) {
        const bf16* p = xb + ic * NPIX;
        float in[9];
        in[0] = (rv0 && cv0) ? __bfloat162float(p[-65]) : 0.f;
        in[1] = rv0          ? __bfloat162float(p[-64]) : 0.f;
        in[2] = (rv0 && cv2) ? __bfloat162float(p[-63]) : 0.f;
        in[3] = cv0          ? __bfloat162float(p[-1])  : 0.f;
        in[4] =                __bfloat162float(p[0]);
        in[5] = cv2          ? __bfloat162float(p[1])   : 0.f;
        in[6] = (rv2 && cv0) ? __bfloat162float(p[63])  : 0.f;
        in[7] = rv2          ? __bfloat162float(p[64])  : 0.f;
        in[8] = (rv2 && cv2) ? __bfloat162float(p[65])  : 0.f;
        const float* w = wt + ic * 576;
#pragma unroll
        for (int k = 0; k < 9; ++k) {
            float iv = in[k];
#pragma unroll
            for (int oc = 0; oc < 16; ++oc)
                acc[oc] = fmaf(w[k * 64 + oc], iv, acc[oc]);
        }
    }

    T* ob = (T*)outv + ((size_t)b * 64 + ocBase) * NPIX + row * 64 + col;
#pragma unroll
    for (int oc = 0; oc < 16; ++oc) {
        float a  = ws[OFF_FOLD + 320 + ocBase + oc];
        float bo = ws[OFF_FOLD + 384 + ocBase + oc];
        float y = fmaxf(acc[oc] * a + bo, 0.f);
        stf(ob + oc * NPIX, y);
    }
}

// ---------------------------------------------------------------------------
extern "C" void kernel_launch(void* const* d_in, const int* in_sizes, int n_in,
                              void* d_out, int out_size, void* d_ws, size_t ws_size,
                              hipStream_t stream)
{
    (void)in_sizes; (void)n_in; (void)out_size; (void)ws_size;
    const void* x = d_in[0];
    float* ws = (float*)d_ws;
    bf16* xo  = (bf16*)((char*)d_ws + OFF_XO_BYTES);

    PrepArgs pa;
    // lw1..lv2 = d_in[1..12], gw1..gv2 = d_in[13..24]
    for (int i = 0; i < 24; ++i) pa.p[i] = d_in[1 + i];
    // d_in[25..31]: qw qb kw kb vw vb gamma -> dead code (attention output discarded)
    for (int i = 0; i < 6; ++i)  pa.p[24 + i] = d_in[32 + i];

    k_probe<<<dim3(1), dim3(64), 0, stream>>>((const unsigned*)x, (int*)d_ws);

    k_prep_t<bf16, 1><<<dim3(18), dim3(256), 0, stream>>>(pa, ws);
    k_prep_t<float, 2><<<dim3(18), dim3(256), 0, stream>>>(pa, ws);

    k_means_t<bf16, 1><<<dim3(512), dim3(256), 0, stream>>>(x, ws);
    k_means_t<float, 2><<<dim3(512), dim3(256), 0, stream>>>(x, ws);

    k_gate_t<bf16, 1><<<dim3(256), dim3(128), 0, stream>>>(x, ws, xo);
    k_gate_t<float, 2><<<dim3(256), dim3(128), 0, stream>>>(x, ws, xo);

    k_conv_t<bf16, 1><<<dim3(16, 8, 4), dim3(256), 0, stream>>>(xo, ws, d_out);
    k_conv_t<float, 2><<<dim3(16, 8, 4), dim3(256), 0, stream>>>(xo, ws, d_out);
}

// Round 4
// 193.953 us; speedup vs baseline: 1.5480x; 1.5480x over previous
//
#include <hip/hip_runtime.h>
#include <hip/hip_bf16.h>

// Problem dims: B=8, C=64, H=W=64, INTER=16. Attention branch is dead code
// (its result feeds only the discarded `_dead` tensor).
#define NPIX 4096
#define FEPS 1e-5f

typedef __hip_bfloat16 bf16;
typedef __attribute__((ext_vector_type(8))) short bf16x8;  // 8 bf16 = 4 VGPRs
typedef __attribute__((ext_vector_type(4))) float f32x4;   // MFMA 16x16 acc

// ws layout:
//  word 0 (as int): dtype flag written by r4_probe (1 = bf16, 2 = fp32)
//  float region (element offsets):
#define OFF_FOLD 64     // A1[16] B1[16] A2[64](@32) B2[64](@96) gA1[16](@160) gB1[16](@176) gA2[64](@192) gB2[64](@256) cA[64](@320) cB[64](@384)
#define OFF_G    512    // 512 floats: per (b,c) channel means
#define OFF_LW1  1024
#define OFF_LW2  2048
#define OFF_GW1  3072
#define OFF_GW2  4096   // float region ends at 5120 floats = 20480 B
//  byte offsets:
#define WSWZ_BYTES_OFF 20480   // 36864 ushort (73728 B): conv W in MFMA A-frag order
#define XO_BYTES_OFF   94208   // bf16 xo[8][4096 pix][64 ic] (pixel-major), 4 MB

template<typename T> __device__ __forceinline__ float ldf(const T* p);
template<> __device__ __forceinline__ float ldf<bf16>(const bf16* p)  { return __bfloat162float(*p); }
template<> __device__ __forceinline__ float ldf<float>(const float* p){ return *p; }

template<typename T> __device__ __forceinline__ void stf(T* p, float v);
template<> __device__ __forceinline__ void stf<bf16>(bf16* p, float v)  { *p = __float2bfloat16(v); }
template<> __device__ __forceinline__ void stf<float>(float* p, float v){ *p = v; }

__device__ __forceinline__ unsigned short f2bu(float f) {
    union { bf16 h; unsigned short u; } c; c.h = __float2bfloat16(f); return c.u;
}

// ---------------------------------------------------------------------------
// dtype probe: low 16 bits of each 32-bit word of N(0,1) bf16 data are a bf16
// value (exponent near 127); for fp32 data they are uniform mantissa bits.
// ---------------------------------------------------------------------------
__global__ void r4_probe(const unsigned* __restrict__ x, int* __restrict__ flag)
{
    int t = threadIdx.x;
    unsigned w = x[t];
    unsigned h = w & 0xffffu;
    int e = (int)((h >> 7) & 0xff);
    int hit = (h == 0u || (e >= 96 && e <= 160)) ? 1 : 0;
    unsigned long long m = __ballot(hit);
    if (t == 0) flag[0] = (__popcll(m) >= 40) ? 1 : 2;   // bf16 ~64 hits, fp32 ~16
}

// ---------------------------------------------------------------------------
struct PrepArgs4 { const void* p[30]; };
// slots: 0..5 lw1 lb1 ls1 lbb1 lm1 lv1 | 6..11 lw2 lb2 ls2 lbb2 lm2 lv2
//        12..17 gw1 gb1 gs1 gbb1 gm1 gv1 | 18..23 gw2 gb2 gs2 gbb2 gm2 gv2
//        24..29 cw cb cs cbb cm cv

// prep: blocks 0..15 swizzle conv W into MFMA A-frag order (ushort permute):
//   wswz[(((t*2+s)*4+g)*64 + l)*8 + j] = cw[oc=g*16+(l&15)][ic=s*32+(l>>4)*8+j][t]
// block 16: gate MLP weights -> fp32; block 17: fold BN constants.
template<typename T, int ID>
__global__ void r4_prep(PrepArgs4 a, float* __restrict__ ws,
                        unsigned short* __restrict__ wswz)
{
    if (((const int*)ws)[0] != ID) return;
    const T* lw1  = (const T*)a.p[0];  const T* lb1  = (const T*)a.p[1];
    const T* ls1  = (const T*)a.p[2];  const T* lbb1 = (const T*)a.p[3];
    const T* lm1  = (const T*)a.p[4];  const T* lv1  = (const T*)a.p[5];
    const T* lw2  = (const T*)a.p[6];  const T* lb2  = (const T*)a.p[7];
    const T* ls2  = (const T*)a.p[8];  const T* lbb2 = (const T*)a.p[9];
    const T* lm2  = (const T*)a.p[10]; const T* lv2  = (const T*)a.p[11];
    const T* gw1  = (const T*)a.p[12]; const T* gb1  = (const T*)a.p[13];
    const T* gs1  = (const T*)a.p[14]; const T* gbb1 = (const T*)a.p[15];
    const T* gm1  = (const T*)a.p[16]; const T* gv1  = (const T*)a.p[17];
    const T* gw2  = (const T*)a.p[18]; const T* gb2  = (const T*)a.p[19];
    const T* gs2  = (const T*)a.p[20]; const T* gbb2 = (const T*)a.p[21];
    const T* gm2  = (const T*)a.p[22]; const T* gv2  = (const T*)a.p[23];
    const T* cw   = (const T*)a.p[24]; const T* cb   = (const T*)a.p[25];
    const T* cs   = (const T*)a.p[26]; const T* cbb  = (const T*)a.p[27];
    const T* cm   = (const T*)a.p[28]; const T* cv   = (const T*)a.p[29];

    int bx = blockIdx.x;
    int tid = threadIdx.x;
    if (bx < 16) {
        for (int e = tid; e < 2304; e += 256) {
            int E = bx * 2304 + e;
            int j = E & 7;
            int F = E >> 3;
            int l = F & 63;
            int g = (F >> 6) & 3;
            int ts = F >> 8;          // t*2+s
            int s = ts & 1;
            int t = ts >> 1;
            int oc = g * 16 + (l & 15);
            int ic = s * 32 + (l >> 4) * 8 + j;
            wswz[E] = f2bu(ldf(cw + (oc * 64 + ic) * 9 + t));
        }
    } else if (bx == 16) {
        for (int e = tid; e < 4096; e += 256) {
            if (e < 1024)      ws[OFF_LW1 + e]        = ldf(lw1 + e);
            else if (e < 2048) ws[OFF_LW2 + e - 1024] = ldf(lw2 + e - 1024);
            else if (e < 3072) ws[OFF_GW1 + e - 2048] = ldf(gw1 + e - 2048);
            else               ws[OFF_GW2 + e - 3072] = ldf(gw2 + e - 3072);
        }
    } else {
        if (tid < 16) {
            float inv = ldf(ls1 + tid) * rsqrtf(ldf(lv1 + tid) + FEPS);
            ws[OFF_FOLD + 0  + tid] = inv;
            ws[OFF_FOLD + 16 + tid] = ldf(lb1 + tid) * inv + ldf(lbb1 + tid) - ldf(lm1 + tid) * inv;
            float ginv = ldf(gs1 + tid) * rsqrtf(ldf(gv1 + tid) + FEPS);
            ws[OFF_FOLD + 160 + tid] = ginv;
            ws[OFF_FOLD + 176 + tid] = ldf(gb1 + tid) * ginv + ldf(gbb1 + tid) - ldf(gm1 + tid) * ginv;
        }
        if (tid < 64) {
            float inv2 = ldf(ls2 + tid) * rsqrtf(ldf(lv2 + tid) + FEPS);
            ws[OFF_FOLD + 32 + tid] = inv2;
            ws[OFF_FOLD + 96 + tid] = ldf(lb2 + tid) * inv2 + ldf(lbb2 + tid) - ldf(lm2 + tid) * inv2;
            float ginv2 = ldf(gs2 + tid) * rsqrtf(ldf(gv2 + tid) + FEPS);
            ws[OFF_FOLD + 192 + tid] = ginv2;
            ws[OFF_FOLD + 256 + tid] = ldf(gb2 + tid) * ginv2 + ldf(gbb2 + tid) - ldf(gm2 + tid) * ginv2;
            float cinv = ldf(cs + tid) * rsqrtf(ldf(cv + tid) + FEPS);
            ws[OFF_FOLD + 320 + tid] = cinv;
            ws[OFF_FOLD + 384 + tid] = ldf(cb + tid) * cinv + ldf(cbb + tid) - ldf(cm + tid) * cinv;
        }
    }
}

// ---------------------------------------------------------------------------
// channel means: grid 512 (one per (b,c)), block 256, 16 elements/thread.
// ---------------------------------------------------------------------------
template<typename T, int ID>
__global__ void r4_means(const void* __restrict__ xv, float* __restrict__ ws)
{
    if (((const int*)ws)[0] != ID) return;
    const T* x = (const T*)xv + (size_t)blockIdx.x * NPIX;
    int t = threadIdx.x;
    float s = 0.f;
#pragma unroll
    for (int i = 0; i < 16; ++i) s += ldf(x + t * 16 + i);
#pragma unroll
    for (int off = 32; off > 0; off >>= 1) s += __shfl_down(s, off, 64);
    __shared__ float red[4];
    if ((t & 63) == 0) red[t >> 6] = s;
    __syncthreads();
    if (t == 0)
        ws[OFF_G + blockIdx.x] = (red[0] + red[1] + red[2] + red[3]) * (1.0f / 4096.0f);
}

// ---------------------------------------------------------------------------
// gate: local MLP + global MLP + sigmoid -> xo[b][pix][ic] (bf16, packed uint4)
// grid 256 x 128 threads: 128 consecutive pixels of one image per block.
// ---------------------------------------------------------------------------
template<typename T, int ID>
__global__ void r4_gate(const void* __restrict__ xv, float* __restrict__ ws,
                        uint4* __restrict__ xo)
{
    if (((const int*)ws)[0] != ID) return;
    int b = blockIdx.x >> 5;
    int n = (blockIdx.x & 31) * 128 + threadIdx.x;
    int tid = threadIdx.x;

    __shared__ float t1[16];
    __shared__ float xg[64];
    if (tid < 16) {
        float s = 0.f;
#pragma unroll
        for (int c = 0; c < 64; ++c)
            s += ws[OFF_GW1 + tid * 64 + c] * ws[OFF_G + b * 64 + c];
        float z = ws[OFF_FOLD + 160 + tid] * s + ws[OFF_FOLD + 176 + tid];
        t1[tid] = fmaxf(z, 0.f);
    }
    __syncthreads();
    if (tid < 64) {
        float s = 0.f;
#pragma unroll
        for (int j = 0; j < 16; ++j)
            s += ws[OFF_GW2 + tid * 16 + j] * t1[j];
        xg[tid] = ws[OFF_FOLD + 192 + tid] * s + ws[OFF_FOLD + 256 + tid];
    }
    __syncthreads();

    const T* xb = (const T*)xv + (size_t)b * 64 * NPIX + n;
    float xr[64];
#pragma unroll
    for (int c = 0; c < 64; ++c) xr[c] = ldf(xb + c * NPIX);

    float h[16];
#pragma unroll
    for (int i = 0; i < 16; ++i) {
        float s = 0.f;
#pragma unroll
        for (int c = 0; c < 64; ++c) s += ws[OFF_LW1 + i * 64 + c] * xr[c];
        float z = ws[OFF_FOLD + 0 + i] * s + ws[OFF_FOLD + 16 + i];
        h[i] = fmaxf(z, 0.f);
    }

    uint4* xop = xo + ((size_t)b * NPIX + n) * 8;   // 128 B per pixel
#pragma unroll
    for (int cg = 0; cg < 8; ++cg) {
        unsigned v[8];
#pragma unroll
        for (int j = 0; j < 8; ++j) {
            int c = cg * 8 + j;
            float s = 0.f;
#pragma unroll
            for (int k = 0; k < 16; ++k) s += ws[OFF_LW2 + c * 16 + k] * h[k];
            float z = ws[OFF_FOLD + 32 + c] * s + ws[OFF_FOLD + 96 + c] + xg[c];
            float sg = 1.0f / (1.0f + __expf(-z));
            v[j] = (unsigned)f2bu(xr[c] * sg);
        }
        uint4 pk;
        pk.x = v[0] | (v[1] << 16);
        pk.y = v[2] | (v[3] << 16);
        pk.z = v[4] | (v[5] << 16);
        pk.w = v[6] | (v[7] << 16);
        xop[cg] = pk;
    }
}

// ---------------------------------------------------------------------------
// conv3x3 as implicit GEMM on MFMA 16x16x32 bf16.
// Tile: 32 pixels (half image-row) x 64 oc. WG = 128 thr = 2 waves; wave w
// handles oc groups {2w, 2w+1}. Grid = 8 img * 64 rows * 2 halves = 1024 WGs.
// A-frags from pre-swizzled wswz; B-frags straight from global xo[pix][ic]
// (one dwordx4 per lane). Row-border taps skip uniformly per WG; col-border
// lanes clamp address + zero the fragment.
// C/D layout (m89): col(n=pixel)=lane&15, row(m=oc)=(lane>>4)*4+reg.
// ---------------------------------------------------------------------------
template<typename T, int ID>
__global__ __launch_bounds__(128)
void r4_conv(const bf16x8* __restrict__ wsw, const float* __restrict__ ws,
             const char* __restrict__ xob_base, void* __restrict__ outv)
{
    if (((const int*)ws)[0] != ID) return;
    int bx  = blockIdx.x;
    int b   = bx >> 7;
    int r   = (bx >> 1) & 63;
    int c0  = (bx & 1) * 32;
    int tid = threadIdx.x;
    int w   = tid >> 6;
    int l   = tid & 63;
    int a   = l & 15;
    int q   = l >> 4;

    const char* xob = xob_base + (size_t)b * NPIX * 128;  // 128 B per pixel

    int  colOff[3][2];
    bool edge[3][2];
#pragma unroll
    for (int dci = 0; dci < 3; ++dci)
#pragma unroll
        for (int nf = 0; nf < 2; ++nf) {
            int c = c0 + nf * 16 + a + (dci - 1);
            edge[dci][nf] = (c < 0) || (c > 63);
            c = min(63, max(0, c));
            colOff[dci][nf] = c << 7;
        }

    const bf16x8 zf = {0, 0, 0, 0, 0, 0, 0, 0};
    f32x4 acc[2][2] = {};   // [oc-group-half][pixel-nf]

#pragma unroll
    for (int t = 0; t < 9; ++t) {
        const int dr  = t / 3 - 1;
        const int dci = t % 3;
        int rr = r + dr;
        if (rr < 0 || rr > 63) continue;           // uniform per WG
        const char* rowp = xob + rr * 8192;
#pragma unroll
        for (int s = 0; s < 2; ++s) {
            bf16x8 A0 = wsw[((t * 2 + s) * 4 + 2 * w + 0) * 64 + l];
            bf16x8 A1 = wsw[((t * 2 + s) * 4 + 2 * w + 1) * 64 + l];
            int sq = s * 64 + q * 16;
#pragma unroll
            for (int nf = 0; nf < 2; ++nf) {
                bf16x8 B = *(const bf16x8*)(rowp + colOff[dci][nf] + sq);
                if (dci != 1) { if (edge[dci][nf]) B = zf; }
                acc[0][nf] = __builtin_amdgcn_mfma_f32_16x16x32_bf16(A0, B, acc[0][nf], 0, 0, 0);
                acc[1][nf] = __builtin_amdgcn_mfma_f32_16x16x32_bf16(A1, B, acc[1][nf], 0, 0, 0);
            }
        }
    }

    const float* cA = ws + OFF_FOLD + 320;
    const float* cB = ws + OFF_FOLD + 384;
    int pixBase = r * 64 + c0;
#pragma unroll
    for (int gi = 0; gi < 2; ++gi) {
        int g = 2 * w + gi;
#pragma unroll
        for (int reg = 0; reg < 4; ++reg) {
            int oc = g * 16 + q * 4 + reg;
            float Af = cA[oc];
            float Bf = cB[oc];
#pragma unroll
            for (int nf = 0; nf < 2; ++nf) {
                int pix = pixBase + nf * 16 + a;
                float y = fmaxf(acc[gi][nf][reg] * Af + Bf, 0.f);
                stf((T*)outv + ((size_t)b * 64 + oc) * NPIX + pix, y);
            }
        }
    }
}

// ---------------------------------------------------------------------------
extern "C" void kernel_launch(void* const* d_in, const int* in_sizes, int n_in,
                              void* d_out, int out_size, void* d_ws, size_t ws_size,
                              hipStream_t stream)
{
    (void)in_sizes; (void)n_in; (void)out_size; (void)ws_size;
    const void* x = d_in[0];
    float* ws = (float*)d_ws;
    unsigned short* wswz = (unsigned short*)((char*)d_ws + WSWZ_BYTES_OFF);
    char* xo = (char*)d_ws + XO_BYTES_OFF;

    PrepArgs4 pa;
    // lw1..lv2 = d_in[1..12], gw1..gv2 = d_in[13..24]
    for (int i = 0; i < 24; ++i) pa.p[i] = d_in[1 + i];
    // d_in[25..31]: qw qb kw kb vw vb gamma -> dead code (attention output discarded)
    for (int i = 0; i < 6; ++i)  pa.p[24 + i] = d_in[32 + i];

    r4_probe<<<dim3(1), dim3(64), 0, stream>>>((const unsigned*)x, (int*)d_ws);

    r4_prep<bf16, 1><<<dim3(18), dim3(256), 0, stream>>>(pa, ws, wswz);
    r4_prep<float, 2><<<dim3(18), dim3(256), 0, stream>>>(pa, ws, wswz);

    r4_means<bf16, 1><<<dim3(512), dim3(256), 0, stream>>>(x, ws);
    r4_means<float, 2><<<dim3(512), dim3(256), 0, stream>>>(x, ws);

    r4_gate<bf16, 1><<<dim3(256), dim3(128), 0, stream>>>(x, ws, (uint4*)xo);
    r4_gate<float, 2><<<dim3(256), dim3(128), 0, stream>>>(x, ws, (uint4*)xo);

    r4_conv<bf16, 1><<<dim3(1024), dim3(128), 0, stream>>>(
        (const bf16x8*)wswz, ws, xo, d_out);
    r4_conv<float, 2><<<dim3(1024), dim3(128), 0, stream>>>(
        (const bf16x8*)wswz, ws, xo, d_out);
}

// Round 5
// 188.839 us; speedup vs baseline: 1.5899x; 1.0271x over previous
//
#include <hip/hip_runtime.h>
#include <hip/hip_bf16.h>

// Problem dims: B=8, C=64, H=W=64, INTER=16. Attention branch is dead code
// (its result feeds only the discarded `_dead` tensor).
#define NPIX 4096
#define FEPS 1e-5f

typedef __hip_bfloat16 bf16;
typedef __attribute__((ext_vector_type(8))) short bf16x8;  // 8 bf16 = 4 VGPRs
typedef __attribute__((ext_vector_type(4))) float f32x4;   // MFMA 16x16 acc

// ws layout:
//  word 0 (as int): dtype flag written by r5_probe (1 = bf16, 2 = fp32)
//  float region (element offsets):
#define OFF_FOLD 64     // A1[16] B1[16] A2[64](@32) B2[64](@96) gA1(@160) gB1(@176) gA2(@192) gB2(@256) cA(@320) cB(@384)
#define OFF_G    512    // 512 floats: per (b,c) channel means
#define OFF_LW1  1024
#define OFF_LW2  2048
#define OFF_GW1  3072
#define OFF_GW2  4096   // float region ends at 5120 floats = 20480 B
//  byte offsets:
#define WSWZ_BYTES_OFF 20480   // 36864 ushort (73728 B): conv W in MFMA A-frag order
#define XO_BYTES_OFF   94208   // bf16 xo[8][4096 pix][64 ic] (pixel-major), 4 MB

template<typename T> __device__ __forceinline__ float ldf(const T* p);
template<> __device__ __forceinline__ float ldf<bf16>(const bf16* p)  { return __bfloat162float(*p); }
template<> __device__ __forceinline__ float ldf<float>(const float* p){ return *p; }

template<typename T> __device__ __forceinline__ void stf(T* p, float v);
template<> __device__ __forceinline__ void stf<bf16>(bf16* p, float v)  { *p = __float2bfloat16(v); }
template<> __device__ __forceinline__ void stf<float>(float* p, float v){ *p = v; }

__device__ __forceinline__ unsigned short f2bu(float f) {
    union { bf16 h; unsigned short u; } c; c.h = __float2bfloat16(f); return c.u;
}
__device__ __forceinline__ float blo(unsigned u) {
    union { unsigned i; float f; } c; c.i = u << 16; return c.f;
}
__device__ __forceinline__ float bhi(unsigned u) {
    union { unsigned i; float f; } c; c.i = u & 0xffff0000u; return c.f;
}

// ---------------------------------------------------------------------------
// dtype probe: low 16 bits of each 32-bit word of N(0,1) bf16 data are a bf16
// value (exponent near 127); for fp32 data they are uniform mantissa bits.
// ---------------------------------------------------------------------------
__global__ void r5_probe(const unsigned* __restrict__ x, int* __restrict__ flag)
{
    int t = threadIdx.x;
    unsigned w = x[t];
    unsigned h = w & 0xffffu;
    int e = (int)((h >> 7) & 0xff);
    int hit = (h == 0u || (e >= 96 && e <= 160)) ? 1 : 0;
    unsigned long long m = __ballot(hit);
    if (t == 0) flag[0] = (__popcll(m) >= 40) ? 1 : 2;   // bf16 ~64 hits, fp32 ~16
}

// ---------------------------------------------------------------------------
struct PrepArgs5 { const void* p[30]; };
// slots: 0..5 lw1 lb1 ls1 lbb1 lm1 lv1 | 6..11 lw2 lb2 ls2 lbb2 lm2 lv2
//        12..17 gw1 gb1 gs1 gbb1 gm1 gv1 | 18..23 gw2 gb2 gs2 gbb2 gm2 gv2
//        24..29 cw cb cs cbb cm cv

// prep body: blocks 0..15 swizzle conv W into MFMA A-frag order:
//   wswz[(((t*2+s)*4+g)*64 + l)*8 + j] = cw[oc=g*16+(l&15)][ic=s*32+(l>>4)*8+j][t]
// block 16: gate MLP weights -> fp32; block 17: fold BN constants.
template<typename T>
__device__ void prep_body(const PrepArgs5& a, float* __restrict__ ws,
                          unsigned short* __restrict__ wswz)
{
    const T* lw1  = (const T*)a.p[0];  const T* lb1  = (const T*)a.p[1];
    const T* ls1  = (const T*)a.p[2];  const T* lbb1 = (const T*)a.p[3];
    const T* lm1  = (const T*)a.p[4];  const T* lv1  = (const T*)a.p[5];
    const T* lw2  = (const T*)a.p[6];  const T* lb2  = (const T*)a.p[7];
    const T* ls2  = (const T*)a.p[8];  const T* lbb2 = (const T*)a.p[9];
    const T* lm2  = (const T*)a.p[10]; const T* lv2  = (const T*)a.p[11];
    const T* gw1  = (const T*)a.p[12]; const T* gb1  = (const T*)a.p[13];
    const T* gs1  = (const T*)a.p[14]; const T* gbb1 = (const T*)a.p[15];
    const T* gm1  = (const T*)a.p[16]; const T* gv1  = (const T*)a.p[17];
    const T* gw2  = (const T*)a.p[18]; const T* gb2  = (const T*)a.p[19];
    const T* gs2  = (const T*)a.p[20]; const T* gbb2 = (const T*)a.p[21];
    const T* gm2  = (const T*)a.p[22]; const T* gv2  = (const T*)a.p[23];
    const T* cw   = (const T*)a.p[24]; const T* cb   = (const T*)a.p[25];
    const T* cs   = (const T*)a.p[26]; const T* cbb  = (const T*)a.p[27];
    const T* cm   = (const T*)a.p[28]; const T* cv   = (const T*)a.p[29];

    int bx = blockIdx.x;
    int tid = threadIdx.x;
    if (bx < 16) {
        for (int e = tid; e < 2304; e += 256) {
            int E = bx * 2304 + e;
            int j = E & 7;
            int F = E >> 3;
            int l = F & 63;
            int g = (F >> 6) & 3;
            int ts = F >> 8;          // t*2+s
            int s = ts & 1;
            int t = ts >> 1;
            int oc = g * 16 + (l & 15);
            int ic = s * 32 + (l >> 4) * 8 + j;
            wswz[E] = f2bu(ldf(cw + (oc * 64 + ic) * 9 + t));
        }
    } else if (bx == 16) {
        for (int e = tid; e < 4096; e += 256) {
            if (e < 1024)      ws[OFF_LW1 + e]        = ldf(lw1 + e);
            else if (e < 2048) ws[OFF_LW2 + e - 1024] = ldf(lw2 + e - 1024);
            else if (e < 3072) ws[OFF_GW1 + e - 2048] = ldf(gw1 + e - 2048);
            else               ws[OFF_GW2 + e - 3072] = ldf(gw2 + e - 3072);
        }
    } else {
        if (tid < 16) {
            float inv = ldf(ls1 + tid) * rsqrtf(ldf(lv1 + tid) + FEPS);
            ws[OFF_FOLD + 0  + tid] = inv;
            ws[OFF_FOLD + 16 + tid] = ldf(lb1 + tid) * inv + ldf(lbb1 + tid) - ldf(lm1 + tid) * inv;
            float ginv = ldf(gs1 + tid) * rsqrtf(ldf(gv1 + tid) + FEPS);
            ws[OFF_FOLD + 160 + tid] = ginv;
            ws[OFF_FOLD + 176 + tid] = ldf(gb1 + tid) * ginv + ldf(gbb1 + tid) - ldf(gm1 + tid) * ginv;
        }
        if (tid < 64) {
            float inv2 = ldf(ls2 + tid) * rsqrtf(ldf(lv2 + tid) + FEPS);
            ws[OFF_FOLD + 32 + tid] = inv2;
            ws[OFF_FOLD + 96 + tid] = ldf(lb2 + tid) * inv2 + ldf(lbb2 + tid) - ldf(lm2 + tid) * inv2;
            float ginv2 = ldf(gs2 + tid) * rsqrtf(ldf(gv2 + tid) + FEPS);
            ws[OFF_FOLD + 192 + tid] = ginv2;
            ws[OFF_FOLD + 256 + tid] = ldf(gb2 + tid) * ginv2 + ldf(gbb2 + tid) - ldf(gm2 + tid) * ginv2;
            float cinv = ldf(cs + tid) * rsqrtf(ldf(cv + tid) + FEPS);
            ws[OFF_FOLD + 320 + tid] = cinv;
            ws[OFF_FOLD + 384 + tid] = ldf(cb + tid) * cinv + ldf(cbb + tid) - ldf(cm + tid) * cinv;
        }
    }
}

__global__ void r5_prep(PrepArgs5 a, float* __restrict__ ws,
                        unsigned short* __restrict__ wswz)
{
    if (((const int*)ws)[0] == 1) prep_body<bf16>(a, ws, wswz);
    else                          prep_body<float>(a, ws, wswz);
}

// ---------------------------------------------------------------------------
// channel means: grid 512 (one per (b,c)), block 256, vectorized loads.
// ---------------------------------------------------------------------------
__global__ void r5_means(const void* __restrict__ xv, float* __restrict__ ws)
{
    int flag = ((const int*)ws)[0];
    int bc = blockIdx.x;
    int t = threadIdx.x;
    float s = 0.f;
    if (flag == 1) {
        const uint4* p = (const uint4*)((const bf16*)xv + (size_t)bc * NPIX);
#pragma unroll
        for (int i = 0; i < 2; ++i) {
            uint4 v = p[t * 2 + i];
            s += blo(v.x) + bhi(v.x) + blo(v.y) + bhi(v.y)
               + blo(v.z) + bhi(v.z) + blo(v.w) + bhi(v.w);
        }
    } else {
        const float4* p = (const float4*)((const float*)xv + (size_t)bc * NPIX);
#pragma unroll
        for (int i = 0; i < 4; ++i) {
            float4 v = p[t * 4 + i];
            s += v.x + v.y + v.z + v.w;
        }
    }
#pragma unroll
    for (int off = 32; off > 0; off >>= 1) s += __shfl_down(s, off, 64);
    __shared__ float red[4];
    if ((t & 63) == 0) red[t >> 6] = s;
    __syncthreads();
    if (t == 0)
        ws[OFF_G + bc] = (red[0] + red[1] + red[2] + red[3]) * (1.0f / 4096.0f);
}

// ---------------------------------------------------------------------------
// gate slow path (fp32 insurance): one pixel per thread, as in r4.
// grid 256 x 128.
// ---------------------------------------------------------------------------
__device__ void gate_slow_f32(const void* __restrict__ xv, float* __restrict__ ws,
                              uint4* __restrict__ xo)
{
    int b = blockIdx.x >> 5;
    int n = (blockIdx.x & 31) * 128 + threadIdx.x;
    int tid = threadIdx.x;

    __shared__ float t1[16];
    __shared__ float xg[64];
    if (tid < 16) {
        float s = 0.f;
#pragma unroll
        for (int c = 0; c < 64; ++c)
            s += ws[OFF_GW1 + tid * 64 + c] * ws[OFF_G + b * 64 + c];
        t1[tid] = fmaxf(ws[OFF_FOLD + 160 + tid] * s + ws[OFF_FOLD + 176 + tid], 0.f);
    }
    __syncthreads();
    if (tid < 64) {
        float s = 0.f;
#pragma unroll
        for (int j = 0; j < 16; ++j) s += ws[OFF_GW2 + tid * 16 + j] * t1[j];
        xg[tid] = ws[OFF_FOLD + 192 + tid] * s + ws[OFF_FOLD + 256 + tid];
    }
    __syncthreads();

    const float* xb = (const float*)xv + (size_t)b * 64 * NPIX + n;
    float xr[64];
#pragma unroll
    for (int c = 0; c < 64; ++c) xr[c] = xb[c * NPIX];

    float h[16];
#pragma unroll
    for (int i = 0; i < 16; ++i) {
        float s = 0.f;
#pragma unroll
        for (int c = 0; c < 64; ++c) s += ws[OFF_LW1 + i * 64 + c] * xr[c];
        h[i] = fmaxf(ws[OFF_FOLD + 0 + i] * s + ws[OFF_FOLD + 16 + i], 0.f);
    }

    uint4* xop = xo + ((size_t)b * NPIX + n) * 8;
#pragma unroll
    for (int cg = 0; cg < 8; ++cg) {
        unsigned v[8];
#pragma unroll
        for (int j = 0; j < 8; ++j) {
            int c = cg * 8 + j;
            float s = 0.f;
#pragma unroll
            for (int k = 0; k < 16; ++k) s += ws[OFF_LW2 + c * 16 + k] * h[k];
            float z = ws[OFF_FOLD + 32 + c] * s + ws[OFF_FOLD + 96 + c] + xg[c];
            v[j] = (unsigned)f2bu(xr[c] / (1.0f + __expf(-z)));
        }
        uint4 pk;
        pk.x = v[0] | (v[1] << 16);
        pk.y = v[2] | (v[3] << 16);
        pk.z = v[4] | (v[5] << 16);
        pk.w = v[6] | (v[7] << 16);
        xop[cg] = pk;
    }
}

// ---------------------------------------------------------------------------
// gate fast path (bf16): LDS-tiled. grid 256 x 128: block = 128 px of one
// image. Coalesced uint4 staging -> LDS -> per-pixel column reads (free
// 2-lane/dword broadcast) -> MLP -> direct uint4 stores (pixel-major xo).
// ---------------------------------------------------------------------------
__global__ __launch_bounds__(128)
void r5_gate(const void* __restrict__ xv, float* __restrict__ ws,
             uint4* __restrict__ xo)
{
    if (((const int*)ws)[0] != 1) { gate_slow_f32(xv, ws, xo); return; }

    int bx = blockIdx.x;
    int b = bx >> 5;
    int pix0 = (bx & 31) * 128;
    int t = threadIdx.x;

    __shared__ float t1[16];
    __shared__ float xg[64];
    __shared__ char tile[64 * 256];   // [c][128 px] bf16, row stride 256 B

    // 1. issue coalesced tile loads (8 independent uint4 / thread)
    const uint4* xsrc = (const uint4*)((const bf16*)xv + (size_t)b * 64 * NPIX + pix0);
    uint4 ld[8];
#pragma unroll
    for (int k = 0; k < 8; ++k) {
        int e = k * 128 + t;          // 0..1023
        int c = e >> 4;               // 16 uint4 per 128-px row
        int u = e & 15;
        ld[k] = xsrc[(size_t)c * 512 + u];
    }
    // 2. overlap: global-MLP layer 1 (uniform s_loads)
    if (t < 16) {
        float s = 0.f;
#pragma unroll
        for (int c = 0; c < 64; ++c)
            s += ws[OFF_GW1 + t * 64 + c] * ws[OFF_G + b * 64 + c];
        t1[t] = fmaxf(ws[OFF_FOLD + 160 + t] * s + ws[OFF_FOLD + 176 + t], 0.f);
    }
    // 3. stage tile
#pragma unroll
    for (int k = 0; k < 8; ++k) {
        int e = k * 128 + t;
        int c = e >> 4;
        int u = e & 15;
        *(uint4*)(tile + c * 256 + u * 16) = ld[k];
    }
    __syncthreads();
    // 4. global-MLP layer 2
    if (t < 64) {
        float s = 0.f;
#pragma unroll
        for (int j = 0; j < 16; ++j) s += ws[OFF_GW2 + t * 16 + j] * t1[j];
        xg[t] = ws[OFF_FOLD + 192 + t] * s + ws[OFF_FOLD + 256 + t];
    }
    // 5. per-pixel column read (conflict-free)
    float xr[64];
#pragma unroll
    for (int c = 0; c < 64; ++c)
        xr[c] = __bfloat162float(*(const bf16*)(tile + c * 256 + t * 2));
    // 6. local MLP layer 1
    float h[16];
#pragma unroll
    for (int i = 0; i < 16; ++i) {
        float s = 0.f;
#pragma unroll
        for (int c = 0; c < 64; ++c) s += ws[OFF_LW1 + i * 64 + c] * xr[c];
        h[i] = fmaxf(ws[OFF_FOLD + 0 + i] * s + ws[OFF_FOLD + 16 + i], 0.f);
    }
    __syncthreads();   // xg visible (also fences tile reads, all done above)
    // 7. layer 2 + gating + packed stores (pixel-major xo, 128 B / pixel)
    uint4* xop = xo + ((size_t)b * NPIX + pix0 + t) * 8;
#pragma unroll
    for (int cg = 0; cg < 8; ++cg) {
        unsigned v[8];
#pragma unroll
        for (int j = 0; j < 8; ++j) {
            int c = cg * 8 + j;
            float s = 0.f;
#pragma unroll
            for (int k = 0; k < 16; ++k) s += ws[OFF_LW2 + c * 16 + k] * h[k];
            float z = ws[OFF_FOLD + 32 + c] * s + ws[OFF_FOLD + 96 + c] + xg[c];
            v[j] = (unsigned)f2bu(xr[c] / (1.0f + __expf(-z)));
        }
        uint4 pk;
        pk.x = v[0] | (v[1] << 16);
        pk.y = v[2] | (v[3] << 16);
        pk.z = v[4] | (v[5] << 16);
        pk.w = v[6] | (v[7] << 16);
        xop[cg] = pk;
    }
}

// ---------------------------------------------------------------------------
// conv3x3 as implicit GEMM on MFMA 16x16x32 bf16 (proven in r4).
// Tile: 32 pixels (half image-row) x 64 oc. WG = 128 thr = 2 waves; wave w
// handles oc groups {2w, 2w+1}. Grid = 8 img * 64 rows * 2 halves = 1024 WGs.
// C/D layout (m89): col(n=pixel)=lane&15, row(m=oc)=(lane>>4)*4+reg.
// ---------------------------------------------------------------------------
template<typename T>
__device__ void conv_body(const bf16x8* __restrict__ wsw, const float* __restrict__ ws,
                          const char* __restrict__ xob_base, void* __restrict__ outv)
{
    int bx  = blockIdx.x;
    int b   = bx >> 7;
    int r   = (bx >> 1) & 63;
    int c0  = (bx & 1) * 32;
    int tid = threadIdx.x;
    int w   = tid >> 6;
    int l   = tid & 63;
    int a   = l & 15;
    int q   = l >> 4;

    const char* xob = xob_base + (size_t)b * NPIX * 128;  // 128 B per pixel

    int  colOff[3][2];
    bool edge[3][2];
#pragma unroll
    for (int dci = 0; dci < 3; ++dci)
#pragma unroll
        for (int nf = 0; nf < 2; ++nf) {
            int c = c0 + nf * 16 + a + (dci - 1);
            edge[dci][nf] = (c < 0) || (c > 63);
            c = min(63, max(0, c));
            colOff[dci][nf] = c << 7;
        }

    const bf16x8 zf = {0, 0, 0, 0, 0, 0, 0, 0};
    f32x4 acc[2][2] = {};   // [oc-group-half][pixel-nf]

#pragma unroll
    for (int t = 0; t < 9; ++t) {
        const int dr  = t / 3 - 1;
        const int dci = t % 3;
        int rr = r + dr;
        if (rr < 0 || rr > 63) continue;           // uniform per WG
        const char* rowp = xob + rr * 8192;
#pragma unroll
        for (int s = 0; s < 2; ++s) {
            bf16x8 A0 = wsw[((t * 2 + s) * 4 + 2 * w + 0) * 64 + l];
            bf16x8 A1 = wsw[((t * 2 + s) * 4 + 2 * w + 1) * 64 + l];
            int sq = s * 64 + q * 16;
#pragma unroll
            for (int nf = 0; nf < 2; ++nf) {
                bf16x8 B = *(const bf16x8*)(rowp + colOff[dci][nf] + sq);
                if (dci != 1) { if (edge[dci][nf]) B = zf; }
                acc[0][nf] = __builtin_amdgcn_mfma_f32_16x16x32_bf16(A0, B, acc[0][nf], 0, 0, 0);
                acc[1][nf] = __builtin_amdgcn_mfma_f32_16x16x32_bf16(A1, B, acc[1][nf], 0, 0, 0);
            }
        }
    }

    const float* cA = ws + OFF_FOLD + 320;
    const float* cB = ws + OFF_FOLD + 384;
    int pixBase = r * 64 + c0;
#pragma unroll
    for (int gi = 0; gi < 2; ++gi) {
        int g = 2 * w + gi;
#pragma unroll
        for (int reg = 0; reg < 4; ++reg) {
            int oc = g * 16 + q * 4 + reg;
            float Af = cA[oc];
            float Bf = cB[oc];
#pragma unroll
            for (int nf = 0; nf < 2; ++nf) {
                int pix = pixBase + nf * 16 + a;
                float y = fmaxf(acc[gi][nf][reg] * Af + Bf, 0.f);
                stf((T*)outv + ((size_t)b * 64 + oc) * NPIX + pix, y);
            }
        }
    }
}

__global__ __launch_bounds__(128)
void r5_conv(const bf16x8* __restrict__ wsw, const float* __restrict__ ws,
             const char* __restrict__ xob_base, void* __restrict__ outv)
{
    if (((const int*)ws)[0] == 1) conv_body<bf16>(wsw, ws, xob_base, outv);
    else                          conv_body<float>(wsw, ws, xob_base, outv);
}

// ---------------------------------------------------------------------------
extern "C" void kernel_launch(void* const* d_in, const int* in_sizes, int n_in,
                              void* d_out, int out_size, void* d_ws, size_t ws_size,
                              hipStream_t stream)
{
    (void)in_sizes; (void)n_in; (void)out_size; (void)ws_size;
    const void* x = d_in[0];
    float* ws = (float*)d_ws;
    unsigned short* wswz = (unsigned short*)((char*)d_ws + WSWZ_BYTES_OFF);
    char* xo = (char*)d_ws + XO_BYTES_OFF;

    PrepArgs5 pa;
    // lw1..lv2 = d_in[1..12], gw1..gv2 = d_in[13..24]
    for (int i = 0; i < 24; ++i) pa.p[i] = d_in[1 + i];
    // d_in[25..31]: qw qb kw kb vw vb gamma -> dead code (attention output discarded)
    for (int i = 0; i < 6; ++i)  pa.p[24 + i] = d_in[32 + i];

    r5_probe<<<dim3(1), dim3(64), 0, stream>>>((const unsigned*)x, (int*)d_ws);
    r5_prep<<<dim3(18), dim3(256), 0, stream>>>(pa, ws, wswz);
    r5_means<<<dim3(512), dim3(256), 0, stream>>>(x, ws);
    r5_gate<<<dim3(256), dim3(128), 0, stream>>>(x, ws, (uint4*)xo);
    r5_conv<<<dim3(1024), dim3(128), 0, stream>>>(
        (const bf16x8*)wswz, ws, xo, d_out);
}

// Round 7
// 185.451 us; speedup vs baseline: 1.6189x; 1.0183x over previous
//
#include <hip/hip_runtime.h>
#include <hip/hip_bf16.h>

// Problem dims: B=8, C=64, H=W=64, INTER=16. Attention branch is dead code
// (its result feeds only the discarded `_dead` tensor).
#define NPIX 4096
#define FEPS 1e-5f

typedef __hip_bfloat16 bf16;
typedef __attribute__((ext_vector_type(8))) short bf16x8;  // 8 bf16 = 4 VGPRs
typedef __attribute__((ext_vector_type(4))) float f32x4;   // MFMA 16x16 acc

// ws layout:
//  word 0 (as int): dtype flag (1 = bf16, 2 = fp32), published by fused k1
//  float region (element offsets):
#define OFF_FOLD 64     // A1[16] B1[16] A2[64](@32) B2[64](@96) gA1(@160) gB1(@176) gA2(@192) gB2(@256) cA(@320) cB(@384)
#define OFF_G    512    // 512 floats: per (b,c) channel means
#define OFF_LW1  1024
#define OFF_LW2  2048
#define OFF_GW1  3072
#define OFF_GW2  4096   // float region ends at 5120 floats = 20480 B
//  byte offsets:
#define WSWZ_BYTES_OFF 20480   // 36864 ushort (73728 B): conv W in MFMA A-frag order
#define XO_BYTES_OFF   94208   // bf16 xo[8][4096 pix][64 ic] (pixel-major), 4 MB

template<typename T> __device__ __forceinline__ float ldf(const T* p);
template<> __device__ __forceinline__ float ldf<bf16>(const bf16* p)  { return __bfloat162float(*p); }
template<> __device__ __forceinline__ float ldf<float>(const float* p){ return *p; }

template<typename T> __device__ __forceinline__ void stf(T* p, float v);
template<> __device__ __forceinline__ void stf<bf16>(bf16* p, float v)  { *p = __float2bfloat16(v); }
template<> __device__ __forceinline__ void stf<float>(float* p, float v){ *p = v; }

__device__ __forceinline__ unsigned short f2bu(float f) {
    union { bf16 h; unsigned short u; } c; c.h = __float2bfloat16(f); return c.u;
}
__device__ __forceinline__ float blo(unsigned u) {
    union { unsigned i; float f; } c; c.i = u << 16; return c.f;
}
__device__ __forceinline__ float bhi(unsigned u) {
    union { unsigned i; float f; } c; c.i = u & 0xffff0000u; return c.f;
}

// dtype probe, callable per-block: low 16 bits of each 32-bit word of N(0,1)
// bf16 data are a bf16 value (exponent near 127); for fp32 data they are
// uniform mantissa bits. Wave 0 ballots, result broadcast via LDS.
__device__ __forceinline__ int probe_flag(const unsigned* __restrict__ x,
                                          int tid, int* sflag)
{
    if (tid < 64) {
        unsigned w = x[tid];
        unsigned h = w & 0xffffu;
        int e = (int)((h >> 7) & 0xff);
        int hit = (h == 0u || (e >= 96 && e <= 160)) ? 1 : 0;
        unsigned long long m = __ballot(hit);
        if (tid == 0) *sflag = (__popcll(m) >= 40) ? 1 : 2;  // bf16 ~64, fp32 ~16
    }
    __syncthreads();
    return *sflag;
}

// ---------------------------------------------------------------------------
struct PrepArgs7 { const void* p[30]; };
// slots: 0..5 lw1 lb1 ls1 lbb1 lm1 lv1 | 6..11 lw2 lb2 ls2 lbb2 lm2 lv2
//        12..17 gw1 gb1 gs1 gbb1 gm1 gv1 | 18..23 gw2 gb2 gs2 gbb2 gm2 gv2
//        24..29 cw cb cs cbb cm cv

// prep body (blocks 0..17): 0..15 swizzle conv W into MFMA A-frag order:
//   wswz[(((t*2+s)*4+g)*64 + l)*8 + j] = cw[oc=g*16+(l&15)][ic=s*32+(l>>4)*8+j][t]
// block 16: gate MLP weights -> fp32; block 17: fold BN constants + publish flag.
template<typename T>
__device__ void prep_body(const PrepArgs7& a, float* __restrict__ ws,
                          unsigned short* __restrict__ wswz, int flag)
{
    const T* lw1  = (const T*)a.p[0];  const T* lb1  = (const T*)a.p[1];
    const T* ls1  = (const T*)a.p[2];  const T* lbb1 = (const T*)a.p[3];
    const T* lm1  = (const T*)a.p[4];  const T* lv1  = (const T*)a.p[5];
    const T* lw2  = (const T*)a.p[6];  const T* lb2  = (const T*)a.p[7];
    const T* ls2  = (const T*)a.p[8];  const T* lbb2 = (const T*)a.p[9];
    const T* lm2  = (const T*)a.p[10]; const T* lv2  = (const T*)a.p[11];
    const T* gw1  = (const T*)a.p[12]; const T* gb1  = (const T*)a.p[13];
    const T* gs1  = (const T*)a.p[14]; const T* gbb1 = (const T*)a.p[15];
    const T* gm1  = (const T*)a.p[16]; const T* gv1  = (const T*)a.p[17];
    const T* gw2  = (const T*)a.p[18]; const T* gb2  = (const T*)a.p[19];
    const T* gs2  = (const T*)a.p[20]; const T* gbb2 = (const T*)a.p[21];
    const T* gm2  = (const T*)a.p[22]; const T* gv2  = (const T*)a.p[23];
    const T* cw   = (const T*)a.p[24]; const T* cb   = (const T*)a.p[25];
    const T* cs   = (const T*)a.p[26]; const T* cbb  = (const T*)a.p[27];
    const T* cm   = (const T*)a.p[28]; const T* cv   = (const T*)a.p[29];

    int bx = blockIdx.x;
    int tid = threadIdx.x;
    if (bx < 16) {
        for (int e = tid; e < 2304; e += 256) {
            int E = bx * 2304 + e;
            int j = E & 7;
            int F = E >> 3;
            int l = F & 63;
            int g = (F >> 6) & 3;
            int ts = F >> 8;          // t*2+s
            int s = ts & 1;
            int t = ts >> 1;
            int oc = g * 16 + (l & 15);
            int ic = s * 32 + (l >> 4) * 8 + j;
            wswz[E] = f2bu(ldf(cw + (oc * 64 + ic) * 9 + t));
        }
    } else if (bx == 16) {
        for (int e = tid; e < 4096; e += 256) {
            if (e < 1024)      ws[OFF_LW1 + e]        = ldf(lw1 + e);
            else if (e < 2048) ws[OFF_LW2 + e - 1024] = ldf(lw2 + e - 1024);
            else if (e < 3072) ws[OFF_GW1 + e - 2048] = ldf(gw1 + e - 2048);
            else               ws[OFF_GW2 + e - 3072] = ldf(gw2 + e - 3072);
        }
    } else {
        if (tid == 0) ((int*)ws)[0] = flag;   // publish for gate/conv kernels
        if (tid < 16) {
            float inv = ldf(ls1 + tid) * rsqrtf(ldf(lv1 + tid) + FEPS);
            ws[OFF_FOLD + 0  + tid] = inv;
            ws[OFF_FOLD + 16 + tid] = ldf(lb1 + tid) * inv + ldf(lbb1 + tid) - ldf(lm1 + tid) * inv;
            float ginv = ldf(gs1 + tid) * rsqrtf(ldf(gv1 + tid) + FEPS);
            ws[OFF_FOLD + 160 + tid] = ginv;
            ws[OFF_FOLD + 176 + tid] = ldf(gb1 + tid) * ginv + ldf(gbb1 + tid) - ldf(gm1 + tid) * ginv;
        }
        if (tid < 64) {
            float inv2 = ldf(ls2 + tid) * rsqrtf(ldf(lv2 + tid) + FEPS);
            ws[OFF_FOLD + 32 + tid] = inv2;
            ws[OFF_FOLD + 96 + tid] = ldf(lb2 + tid) * inv2 + ldf(lbb2 + tid) - ldf(lm2 + tid) * inv2;
            float ginv2 = ldf(gs2 + tid) * rsqrtf(ldf(gv2 + tid) + FEPS);
            ws[OFF_FOLD + 192 + tid] = ginv2;
            ws[OFF_FOLD + 256 + tid] = ldf(gb2 + tid) * ginv2 + ldf(gbb2 + tid) - ldf(gm2 + tid) * ginv2;
            float cinv = ldf(cs + tid) * rsqrtf(ldf(cv + tid) + FEPS);
            ws[OFF_FOLD + 320 + tid] = cinv;
            ws[OFF_FOLD + 384 + tid] = ldf(cb + tid) * cinv + ldf(cbb + tid) - ldf(cm + tid) * cinv;
        }
    }
}

// ---------------------------------------------------------------------------
// fused k1: grid 530 x 256. Every block self-probes the dtype (cheap, L2-hot).
//  blocks 0..17  : prep (weight swizzle / MLP weights / BN folds + flag)
//  blocks 18..529: channel mean for bc = bx-18 (vectorized loads)
// ---------------------------------------------------------------------------
__global__ void r7_prep_means(PrepArgs7 a, const void* __restrict__ xv,
                              float* __restrict__ ws,
                              unsigned short* __restrict__ wswz)
{
    __shared__ int sflag;
    int t = threadIdx.x;
    int flag = probe_flag((const unsigned*)xv, t, &sflag);
    int bx = blockIdx.x;

    if (bx < 18) {
        if (flag == 1) prep_body<bf16>(a, ws, wswz, flag);
        else           prep_body<float>(a, ws, wswz, flag);
        return;
    }

    int bc = bx - 18;
    float s = 0.f;
    if (flag == 1) {
        const uint4* p = (const uint4*)((const bf16*)xv + (size_t)bc * NPIX);
#pragma unroll
        for (int i = 0; i < 2; ++i) {
            uint4 v = p[t * 2 + i];
            s += blo(v.x) + bhi(v.x) + blo(v.y) + bhi(v.y)
               + blo(v.z) + bhi(v.z) + blo(v.w) + bhi(v.w);
        }
    } else {
        const float4* p = (const float4*)((const float*)xv + (size_t)bc * NPIX);
#pragma unroll
        for (int i = 0; i < 4; ++i) {
            float4 v = p[t * 4 + i];
            s += v.x + v.y + v.z + v.w;
        }
    }
#pragma unroll
    for (int off = 32; off > 0; off >>= 1) s += __shfl_down(s, off, 64);
    __shared__ float red[4];
    if ((t & 63) == 0) red[t >> 6] = s;
    __syncthreads();
    if (t == 0)
        ws[OFF_G + bc] = (red[0] + red[1] + red[2] + red[3]) * (1.0f / 4096.0f);
}

// ---------------------------------------------------------------------------
// gate slow path (fp32 insurance): one pixel per thread. grid 256 x 128.
// ---------------------------------------------------------------------------
__device__ void gate_slow_f32(const void* __restrict__ xv, float* __restrict__ ws,
                              uint4* __restrict__ xo)
{
    int b = blockIdx.x >> 5;
    int n = (blockIdx.x & 31) * 128 + threadIdx.x;
    int tid = threadIdx.x;

    __shared__ float t1[16];
    __shared__ float xg[64];
    if (tid < 16) {
        float s = 0.f;
#pragma unroll
        for (int c = 0; c < 64; ++c)
            s += ws[OFF_GW1 + tid * 64 + c] * ws[OFF_G + b * 64 + c];
        t1[tid] = fmaxf(ws[OFF_FOLD + 160 + tid] * s + ws[OFF_FOLD + 176 + tid], 0.f);
    }
    __syncthreads();
    if (tid < 64) {
        float s = 0.f;
#pragma unroll
        for (int j = 0; j < 16; ++j) s += ws[OFF_GW2 + tid * 16 + j] * t1[j];
        xg[tid] = ws[OFF_FOLD + 192 + tid] * s + ws[OFF_FOLD + 256 + tid];
    }
    __syncthreads();

    const float* xb = (const float*)xv + (size_t)b * 64 * NPIX + n;
    float xr[64];
#pragma unroll
    for (int c = 0; c < 64; ++c) xr[c] = xb[c * NPIX];

    float h[16];
#pragma unroll
    for (int i = 0; i < 16; ++i) {
        float s = 0.f;
#pragma unroll
        for (int c = 0; c < 64; ++c) s += ws[OFF_LW1 + i * 64 + c] * xr[c];
        h[i] = fmaxf(ws[OFF_FOLD + 0 + i] * s + ws[OFF_FOLD + 16 + i], 0.f);
    }

    uint4* xop = xo + ((size_t)b * NPIX + n) * 8;
#pragma unroll
    for (int cg = 0; cg < 8; ++cg) {
        unsigned v[8];
#pragma unroll
        for (int j = 0; j < 8; ++j) {
            int c = cg * 8 + j;
            float s = 0.f;
#pragma unroll
            for (int k = 0; k < 16; ++k) s += ws[OFF_LW2 + c * 16 + k] * h[k];
            float z = ws[OFF_FOLD + 32 + c] * s + ws[OFF_FOLD + 96 + c] + xg[c];
            v[j] = (unsigned)f2bu(xr[c] / (1.0f + __expf(-z)));
        }
        uint4 pk;
        pk.x = v[0] | (v[1] << 16);
        pk.y = v[2] | (v[3] << 16);
        pk.z = v[4] | (v[5] << 16);
        pk.w = v[6] | (v[7] << 16);
        xop[cg] = pk;
    }
}

// ---------------------------------------------------------------------------
// gate fast path (bf16): LDS-tiled (proven in r5). grid 256 x 128: block =
// 128 px of one image. Coalesced uint4 staging -> LDS -> per-pixel column
// reads -> MLP -> packed uint4 stores into pixel-major xo.
// ---------------------------------------------------------------------------
__global__ __launch_bounds__(128)
void r7_gate(const void* __restrict__ xv, float* __restrict__ ws,
             uint4* __restrict__ xo)
{
    if (((const int*)ws)[0] != 1) { gate_slow_f32(xv, ws, xo); return; }

    int bx = blockIdx.x;
    int b = bx >> 5;
    int pix0 = (bx & 31) * 128;
    int t = threadIdx.x;

    __shared__ float t1[16];
    __shared__ float xg[64];
    __shared__ char tile[64 * 256];   // [c][128 px] bf16, row stride 256 B

    // 1. issue coalesced tile loads (8 independent uint4 / thread)
    const uint4* xsrc = (const uint4*)((const bf16*)xv + (size_t)b * 64 * NPIX + pix0);
    uint4 ld[8];
#pragma unroll
    for (int k = 0; k < 8; ++k) {
        int e = k * 128 + t;          // 0..1023
        int c = e >> 4;               // 16 uint4 per 128-px row
        int u = e & 15;
        ld[k] = xsrc[(size_t)c * 512 + u];
    }
    // 2. overlap: global-MLP layer 1 (uniform loads)
    if (t < 16) {
        float s = 0.f;
#pragma unroll
        for (int c = 0; c < 64; ++c)
            s += ws[OFF_GW1 + t * 64 + c] * ws[OFF_G + b * 64 + c];
        t1[t] = fmaxf(ws[OFF_FOLD + 160 + t] * s + ws[OFF_FOLD + 176 + t], 0.f);
    }
    // 3. stage tile
#pragma unroll
    for (int k = 0; k < 8; ++k) {
        int e = k * 128 + t;
        int c = e >> 4;
        int u = e & 15;
        *(uint4*)(tile + c * 256 + u * 16) = ld[k];
    }
    __syncthreads();
    // 4. global-MLP layer 2
    if (t < 64) {
        float s = 0.f;
#pragma unroll
        for (int j = 0; j < 16; ++j) s += ws[OFF_GW2 + t * 16 + j] * t1[j];
        xg[t] = ws[OFF_FOLD + 192 + t] * s + ws[OFF_FOLD + 256 + t];
    }
    // 5. per-pixel column read
    float xr[64];
#pragma unroll
    for (int c = 0; c < 64; ++c)
        xr[c] = __bfloat162float(*(const bf16*)(tile + c * 256 + t * 2));
    // 6. local MLP layer 1
    float h[16];
#pragma unroll
    for (int i = 0; i < 16; ++i) {
        float s = 0.f;
#pragma unroll
        for (int c = 0; c < 64; ++c) s += ws[OFF_LW1 + i * 64 + c] * xr[c];
        h[i] = fmaxf(ws[OFF_FOLD + 0 + i] * s + ws[OFF_FOLD + 16 + i], 0.f);
    }
    __syncthreads();   // xg visible
    // 7. layer 2 + gating + packed stores (pixel-major xo, 128 B / pixel)
    uint4* xop = xo + ((size_t)b * NPIX + pix0 + t) * 8;
#pragma unroll
    for (int cg = 0; cg < 8; ++cg) {
        unsigned v[8];
#pragma unroll
        for (int j = 0; j < 8; ++j) {
            int c = cg * 8 + j;
            float s = 0.f;
#pragma unroll
            for (int k = 0; k < 16; ++k) s += ws[OFF_LW2 + c * 16 + k] * h[k];
            float z = ws[OFF_FOLD + 32 + c] * s + ws[OFF_FOLD + 96 + c] + xg[c];
            v[j] = (unsigned)f2bu(xr[c] / (1.0f + __expf(-z)));
        }
        uint4 pk;
        pk.x = v[0] | (v[1] << 16);
        pk.y = v[2] | (v[3] << 16);
        pk.z = v[4] | (v[5] << 16);
        pk.w = v[6] | (v[7] << 16);
        xop[cg] = pk;
    }
}

// ---------------------------------------------------------------------------
// conv3x3 as implicit GEMM on MFMA 16x16x32 bf16 (proven in r4/r5).
// Tile: 32 pixels (half image-row) x 64 oc. WG = 128 thr = 2 waves; wave w
// handles oc groups {2w, 2w+1}. Grid = 8 img * 64 rows * 2 halves = 1024 WGs.
// C/D layout (m89): col(n=pixel)=lane&15, row(m=oc)=(lane>>4)*4+reg.
// ---------------------------------------------------------------------------
template<typename T>
__device__ void conv_body(const bf16x8* __restrict__ wsw, const float* __restrict__ ws,
                          const char* __restrict__ xob_base, void* __restrict__ outv)
{
    int bx  = blockIdx.x;
    int b   = bx >> 7;
    int r   = (bx >> 1) & 63;
    int c0  = (bx & 1) * 32;
    int tid = threadIdx.x;
    int w   = tid >> 6;
    int l   = tid & 63;
    int a   = l & 15;
    int q   = l >> 4;

    const char* xob = xob_base + (size_t)b * NPIX * 128;  // 128 B per pixel

    int  colOff[3][2];
    bool edge[3][2];
#pragma unroll
    for (int dci = 0; dci < 3; ++dci)
#pragma unroll
        for (int nf = 0; nf < 2; ++nf) {
            int c = c0 + nf * 16 + a + (dci - 1);
            edge[dci][nf] = (c < 0) || (c > 63);
            c = min(63, max(0, c));
            colOff[dci][nf] = c << 7;
        }

    const bf16x8 zf = {0, 0, 0, 0, 0, 0, 0, 0};
    f32x4 acc[2][2] = {};   // [oc-group-half][pixel-nf]

#pragma unroll
    for (int t = 0; t < 9; ++t) {
        const int dr  = t / 3 - 1;
        const int dci = t % 3;
        int rr = r + dr;
        if (rr < 0 || rr > 63) continue;           // uniform per WG
        const char* rowp = xob + rr * 8192;
#pragma unroll
        for (int s = 0; s < 2; ++s) {
            bf16x8 A0 = wsw[((t * 2 + s) * 4 + 2 * w + 0) * 64 + l];
            bf16x8 A1 = wsw[((t * 2 + s) * 4 + 2 * w + 1) * 64 + l];
            int sq = s * 64 + q * 16;
#pragma unroll
            for (int nf = 0; nf < 2; ++nf) {
                bf16x8 B = *(const bf16x8*)(rowp + colOff[dci][nf] + sq);
                if (dci != 1) { if (edge[dci][nf]) B = zf; }
                acc[0][nf] = __builtin_amdgcn_mfma_f32_16x16x32_bf16(A0, B, acc[0][nf], 0, 0, 0);
                acc[1][nf] = __builtin_amdgcn_mfma_f32_16x16x32_bf16(A1, B, acc[1][nf], 0, 0, 0);
            }
        }
    }

    const float* cA = ws + OFF_FOLD + 320;
    const float* cB = ws + OFF_FOLD + 384;
    int pixBase = r * 64 + c0;
#pragma unroll
    for (int gi = 0; gi < 2; ++gi) {
        int g = 2 * w + gi;
#pragma unroll
        for (int reg = 0; reg < 4; ++reg) {
            int oc = g * 16 + q * 4 + reg;
            float Af = cA[oc];
            float Bf = cB[oc];
#pragma unroll
            for (int nf = 0; nf < 2; ++nf) {
                int pix = pixBase + nf * 16 + a;
                float y = fmaxf(acc[gi][nf][reg] * Af + Bf, 0.f);
                stf((T*)outv + ((size_t)b * 64 + oc) * NPIX + pix, y);
            }
        }
    }
}

__global__ __launch_bounds__(128)
void r7_conv(const bf16x8* __restrict__ wsw, const float* __restrict__ ws,
             const char* __restrict__ xob_base, void* __restrict__ outv)
{
    if (((const int*)ws)[0] == 1) conv_body<bf16>(wsw, ws, xob_base, outv);
    else                          conv_body<float>(wsw, ws, xob_base, outv);
}

// ---------------------------------------------------------------------------
extern "C" void kernel_launch(void* const* d_in, const int* in_sizes, int n_in,
                              void* d_out, int out_size, void* d_ws, size_t ws_size,
                              hipStream_t stream)
{
    (void)in_sizes; (void)n_in; (void)out_size; (void)ws_size;
    const void* x = d_in[0];
    float* ws = (float*)d_ws;
    unsigned short* wswz = (unsigned short*)((char*)d_ws + WSWZ_BYTES_OFF);
    char* xo = (char*)d_ws + XO_BYTES_OFF;

    PrepArgs7 pa;
    // lw1..lv2 = d_in[1..12], gw1..gv2 = d_in[13..24]
    for (int i = 0; i < 24; ++i) pa.p[i] = d_in[1 + i];
    // d_in[25..31]: qw qb kw kb vw vb gamma -> dead code (attention output discarded)
    for (int i = 0; i < 6; ++i)  pa.p[24 + i] = d_in[32 + i];

    r7_prep_means<<<dim3(530), dim3(256), 0, stream>>>(pa, x, ws, wswz);
    r7_gate<<<dim3(256), dim3(128), 0, stream>>>(x, ws, (uint4*)xo);
    r7_conv<<<dim3(1024), dim3(128), 0, stream>>>(
        (const bf16x8*)wswz, ws, xo, d_out);
}